// Round 22
// baseline (318.028 us; speedup 1.0000x reference)
//
#include <hip/hip_runtime.h>
#include <cstdint>

#define C_ 128
#define L_ 16
#define G_ 4
#define H_ 56
#define W_ 56
#define HW_ 3136
#define WL_F 2048                  // weights [c(32)][dy(8)][dx(8)], 1/32 folded

typedef float f4 __attribute__((ext_vector_type(4)));

// DIRECT-GLOBAL xs: each lane loads its own 16-float window (4 x f4) plus
// 2 x f4 of x1 straight from global, per channel. No xs LDS, no DMA, no
// vmcnt asm, no bank conflicts. Why this won't repeat r7's 276us: r7 put the
// 7 dy-siblings in DIFFERENT blocks (9.4 GB L2 demand = 34 TB/s ceiling);
// here all dy-slots are in ONE block on ONE CU, so the 2 dy-parities in a
// wave read identical x1 addresses (wave-coalesced to one transaction) and
// the xs rows of neighboring dy-slots hit L1 (per-chunk block working set
// ~7 KB << 32 KB L1). LDS keeps only broadcast weights (8 KB).
// Masking: validity (row hh, edge col blocks) is k-invariant per lane ->
// invalid segments read a 256 B zeros region (redirected pointer, inc 0).
__global__ __launch_bounds__(256, 2)
void wcorr(const float* __restrict__ x, const float* __restrict__ wgt,
           float* __restrict__ out, const float* __restrict__ zsrc) {
  __shared__ float lds[WL_F];

  int bid = blockIdx.x;
  // bijective XCD swizzle: nwg = 7168 = 8*896; htile fastest (halo-row reuse)
  int wid = (bid & 7) * 896 + (bid >> 3);
  int htile = wid % 14;
  int rest = wid / 14;             // (b*4+g)*16 + t
  int t = rest & 15;
  int bg = rest >> 4;
  int g = bg & 3;
  int b = bg >> 2;
  int h0 = htile * 4;

  int tid = threadIdx.x;
  int tx = tid & 7;
  int slot = tid >> 3;
  int h = slot & 3;
  int dy = slot >> 2;              // 0..7 (7 = dup of 6, store-masked)
  bool active = (dy < 7) && (tx < 7);
  int dyc = dy < 7 ? dy : 6;
  int txc = tx < 7 ? tx : 6;
  int t1 = t > 0 ? t - 1 : 0;
  int w0 = 8 * txc;
  int hh = h0 + h + dyc - 3;
  bool hv = (hh >= 0) && (hh < H_);

  const size_t cstride = (size_t)L_ * HW_;
  const float* xg = x + ((size_t)b * C_ + (size_t)g * 32) * cstride;

  // per-lane k-invariant window pointers (4 x 4-col blocks at w0-4+4j);
  // invalid -> zsrc (zeros), inc 0.
  const float* xsbase = xg + (size_t)t * HW_ + (size_t)(hv ? hh : 0) * W_;
  const float *p0, *p1, *p2, *p3;
  ptrdiff_t i0, i1, i2, i3;
  {
    bool v0 = hv && (w0 >= 4);          // block at w0-4
    bool v3 = hv && (w0 + 8 < W_);      // block at w0+8 (tx==6 -> cols 56+)
    p0 = v0 ? xsbase + (w0 - 4) : zsrc + (tid & 15) * 4;
    p1 = hv ? xsbase + w0       : zsrc + (tid & 15) * 4;
    p2 = hv ? xsbase + (w0 + 4) : zsrc + (tid & 15) * 4;
    p3 = v3 ? xsbase + (w0 + 8) : zsrc + (tid & 15) * 4;
    i0 = v0 ? (ptrdiff_t)cstride : 0;
    i1 = hv ? (ptrdiff_t)cstride : 0;
    i2 = hv ? (ptrdiff_t)cstride : 0;
    i3 = v3 ? (ptrdiff_t)cstride : 0;
  }
  // x1: always valid; the 2 dy-parities of a wave read the same address
  const float* pa = xg + (size_t)t1 * HW_ + (size_t)(h0 + h) * W_ + w0;
  const float* pb = pa + 4;

  // stage weights once, transposed [c][dy][8], 1/32 folded (pad dx=7 -> 0)
  {
    const float sc = 1.0f / 32.0f;
    const float* wsrc = wgt + (size_t)(g * 32) * (L_ * 49) + t * 49;
    #pragma unroll
    for (int j = 0; j < 8; ++j) {
      int idx = tid + j * 256;
      int c = idx >> 6;
      int rem = idx & 63;
      int dyy = rem >> 3, dxx = rem & 7;
      float v = 0.0f;
      if (dyy < 7 && dxx < 7)
        v = wsrc[(size_t)c * (L_ * 49) + dyy * 7 + dxx] * sc;
      lds[idx] = v;
    }
  }

  float acc[7][8];
  #pragma unroll
  for (int i = 0; i < 7; ++i)
    #pragma unroll
    for (int p = 0; p < 8; ++p) acc[i][p] = 0.0f;

  __syncthreads();                 // weights visible; ONLY barrier

  #pragma unroll 2
  for (int c = 0; c < 32; ++c) {
    f4 q0 = *(const f4*)p0;
    f4 q1 = *(const f4*)p1;
    f4 q2 = *(const f4*)p2;
    f4 q3 = *(const f4*)p3;
    f4 a0 = *(const f4*)pa;
    f4 a1 = *(const f4*)pb;
    p0 += i0; p1 += i1; p2 += i2; p3 += i3;
    pa += cstride; pb += cstride;

    const f4* wl = (const f4*)&lds[c * 64 + dyc * 8];
    f4 W0 = wl[0], W1 = wl[1];
    float w7[7] = {W0.x, W0.y, W0.z, W0.w, W1.x, W1.y, W1.z};

    float rr_[16] = {q0.x, q0.y, q0.z, q0.w, q1.x, q1.y, q1.z, q1.w,
                     q2.x, q2.y, q2.z, q2.w, q3.x, q3.y, q3.z, q3.w};
    float x1v[8] = {a0.x, a0.y, a0.z, a0.w, a1.x, a1.y, a1.z, a1.w};

    // output position w0+p, offset dx reads col (w0+p)+dx-3 -> rr_[p+dx+1]
    #pragma unroll
    for (int dxx = 0; dxx < 7; ++dxx) {
      #pragma unroll
      for (int p = 0; p < 8; ++p) {
        acc[dxx][p] = fmaf(w7[dxx], x1v[p] * rr_[p + dxx + 1], acc[dxx][p]);
      }
    }
  }

  if (active) {
    #pragma unroll
    for (int dxx = 0; dxx < 7; ++dxx) {
      int och = (dy * 7 + dxx) * G_ + g;
      float* op = out + (((size_t)b * 196 + och) * L_ + t) * (size_t)HW_
                      + (size_t)(h0 + h) * W_ + w0;
      f4 o0 = {acc[dxx][0], acc[dxx][1], acc[dxx][2], acc[dxx][3]};
      f4 o1 = {acc[dxx][4], acc[dxx][5], acc[dxx][6], acc[dxx][7]};
      __builtin_nontemporal_store(o0, (f4*)op);
      __builtin_nontemporal_store(o1, (f4*)(op + 4));
    }
  }
}

extern "C" void kernel_launch(void* const* d_in, const int* in_sizes, int n_in,
                              void* d_out, int out_size, void* d_ws, size_t ws_size,
                              hipStream_t stream) {
  const float* x = (const float*)d_in[0];
  const float* w = (const float*)d_in[1];
  float* o = (float*)d_out;
  // 256 B zeros region for redirected (pad/OOB) window segments
  hipMemsetAsync(d_ws, 0, 256, stream);
  dim3 grid(7168), block(256);
  hipLaunchKernelGGL(wcorr, grid, block, 0, stream, x, w, o, (const float*)d_ws);
}

// Round 23
// 220.197 us; speedup vs baseline: 1.4443x; 1.4443x over previous
//
#include <hip/hip_runtime.h>
#include <cstdint>

#define C_ 128
#define L_ 16
#define G_ 4
#define H_ 56
#define W_ 56
#define HW_ 3136
#define CH_ 2                      // channels per chunk
#define NCK_ 16                    // chunks
#define NR_ 5                      // halo rows per wave (r = 2w .. 2w+4)
#define WBUF_F 768                 // 12 rows x 64 floats (rows 10,11 dummy)
#define NBUF_ 3
#define LDS_F (4 * NBUF_ * WBUF_F) // 9216 floats = 36864 B -> 4 blocks/CU

typedef float f4 __attribute__((ext_vector_type(4)));
typedef __attribute__((address_space(3))) uint32_t lds_u32;
typedef const __attribute__((address_space(1))) uint32_t glb_u32;

// r18 base (barrier-free per-wave DMA staging, SMEM weights + cndmask,
// scalar FMA) with CLEAN triple buffering — r19 retried without its two
// poisons (no lgkmcnt(0) drain, no tail-sharing: each wave has 3 disjoint
// 768-float buffers; call-2 overflow lanes land in the SAME buffer's dummy
// rows 10-11). stage(j) issues at iter j-2 -> ~2 iterations (~1500 cyc) of
// slack vs the double buffer's ~600. WAR across buffers is program-order
// safe: iter k-1's ds_reads sample LDS before iter k's stage DMA (issued
// later, lands >=300 cyc after issue) can write buf (k+2)%3.
// vmcnt arithmetic (exact, branchless staging): iter-top queue =
// [stage(k):3][stage(k+1):3][x1(k):4] -> vmcnt(7) drains stage(k). x1
// consumption auto-waits vmcnt(3) (forces stage(k+1) drain — free, issued a
// full iteration earlier). ZERO barriers in the whole kernel.
__global__ __launch_bounds__(256, 2)
void wcorr(const float* __restrict__ x, const float* __restrict__ wgt,
           float* __restrict__ out, const float* __restrict__ zsrc) {
  __shared__ float lds[LDS_F];

  int bid = blockIdx.x;
  // bijective XCD swizzle: nwg = 7168 = 8*896; htile fastest (halo-row reuse)
  int wid = (bid & 7) * 896 + (bid >> 3);
  int htile = wid % 14;
  int rest = wid / 14;             // (b*4+g)*16 + t
  int t = rest & 15;
  int bg = rest >> 4;
  int g = bg & 3;
  int b = bg >> 2;
  int h0 = htile * 4;

  int tid = threadIdx.x;
  int lane = tid & 63;
  int wvu = __builtin_amdgcn_readfirstlane(tid >> 6);  // wave 0..3 (uniform)
  int tx = tid & 7;
  int slot = tid >> 3;
  int h = slot & 3;
  int dy = slot >> 2;              // wave w holds dy in {2w, 2w+1}
  bool active = (dy < 7) && (tx < 7);
  bool hi = (lane >= 32);          // dy parity within the wave
  int dyc = dy < 7 ? dy : 6;
  int txc = tx < 7 ? tx : 6;
  int r = h + dyc;                 // global halo row 0..9
  int lr = r - 2 * wvu;            // local row in wave tile, 0..4
  int t1 = t > 0 ? t - 1 : 0;
  int w0 = 8 * txc;

  const size_t cstride = (size_t)L_ * HW_;
  const float* xg = x + ((size_t)b * C_ + (size_t)g * 32) * cstride;
  float* wreg = &lds[wvu * (NBUF_ * WBUF_F)];

  // branchless per-call staging pointers (k-invariant selection):
  auto mkstage = [&](int j, const float*& sp, ptrdiff_t& inc) {
    int tau = lane + j * 64;
    int row = tau >> 4;
    int ci = (row >= NR_) ? 1 : 0;
    int lrr = row - ci * NR_;
    int rg = 2 * wvu + lrr;
    int vb = (tau & 15) ^ (rg & 7);
    int hh = h0 - 3 + rg;
    bool ok = (row < 2 * NR_) && (vb >= 1) && (vb <= 14)
              && (hh >= 0) && (hh < H_);
    sp = ok ? (xg + (size_t)ci * cstride + (size_t)t * HW_
                  + hh * W_ + (vb * 4 - 4))
            : (zsrc + (lane & 15) * 4);
    inc = ok ? (ptrdiff_t)(CH_ * cstride) : 0;
  };
  const float *sp0, *sp1, *sp2;
  ptrdiff_t in0, in1, in2;
  mkstage(0, sp0, in0);
  mkstage(1, sp1, in1);
  mkstage(2, sp2, in2);

  auto stage_to = [&](int bsel) {
    float* db = wreg + bsel * WBUF_F;
    __builtin_amdgcn_global_load_lds((glb_u32*)sp0, (lds_u32*)(db + 0), 16, 0, 0);
    __builtin_amdgcn_global_load_lds((glb_u32*)sp1, (lds_u32*)(db + 256), 16, 0, 0);
    __builtin_amdgcn_global_load_lds((glb_u32*)sp2, (lds_u32*)(db + 512), 16, 0, 0);
    sp0 += in0; sp1 += in1; sp2 += in2;
  };

  // prologue: chunks 0,1 -> bufs 0,1 (disjoint buffers, no drain needed)
  stage_to(0);
  stage_to(1);

  // wave-uniform weight row bases (SMEM path); dyB clamped for page safety
  int dyA = 2 * wvu;
  int dyB = (2 * wvu + 1 < 7) ? (2 * wvu + 1) : 6;
  const float* wgtg = wgt + (size_t)(g * 32) * (L_ * 49) + t * 49;

  const float* x1c0 = xg + (size_t)t1 * HW_ + (size_t)(h0 + h) * W_ + w0;
  const float* x1c1 = x1c0 + cstride;

  float acc[7][8];
  #pragma unroll
  for (int i = 0; i < 7; ++i)
    #pragma unroll
    for (int p = 0; p < 8; ++p) acc[i][p] = 0.0f;

  int s = r & 7;
  int bcur = 0, bn2 = 2;           // buf(k) = k%3, buf(k+2) = (k+2)%3
  #pragma unroll 1
  for (int k = 0; k < NCK_; ++k) {
    int c0 = k * CH_;
    // x1 loads: queue = [stage(k):3][stage(k+1):3][x1(k):4]
    f4 a00 = *(const f4*)(x1c0);
    f4 a01 = *(const f4*)(x1c0 + 4);
    f4 a10 = *(const f4*)(x1c1);
    f4 a11 = *(const f4*)(x1c1 + 4);
    x1c0 += CH_ * cstride;
    x1c1 += CH_ * cstride;

    __builtin_amdgcn_sched_barrier(0);
    asm volatile("s_waitcnt vmcnt(7)" ::: "memory");  // stage(k) landed
    __builtin_amdgcn_sched_barrier(0);

    const float* base = wreg + bcur * WBUF_F;
    const f4* xsrow0 = (const f4*)(base + lr * 64);
    const f4* xsrow1 = (const f4*)(base + (NR_ + lr) * 64);
    f4 q00 = xsrow0[(2 * txc + 0) ^ s];
    f4 q01 = xsrow0[(2 * txc + 1) ^ s];
    f4 q02 = xsrow0[(2 * txc + 2) ^ s];
    f4 q03 = xsrow0[(2 * txc + 3) ^ s];
    f4 q10 = xsrow1[(2 * txc + 0) ^ s];
    f4 q11 = xsrow1[(2 * txc + 1) ^ s];
    f4 q12 = xsrow1[(2 * txc + 2) ^ s];
    f4 q13 = xsrow1[(2 * txc + 3) ^ s];

    // weights: wave-uniform scalar loads (SMEM) + per-lane-half select
    const float* wc0 = wgtg + (size_t)c0 * (L_ * 49);
    const float* wc1 = wc0 + (L_ * 49);
    float w70[7], w71[7];
    #pragma unroll
    for (int d = 0; d < 7; ++d) {
      float a0w = wc0[dyA * 7 + d], b0w = wc0[dyB * 7 + d];
      float a1w = wc1[dyA * 7 + d], b1w = wc1[dyB * 7 + d];
      w70[d] = hi ? b0w : a0w;
      w71[d] = hi ? b1w : a1w;
    }

    if (k + 2 < NCK_) stage_to(bn2);   // prefetch chunk k+2 (2-iter slack)

    __builtin_amdgcn_s_setprio(1);
    #pragma unroll
    for (int ci = 0; ci < CH_; ++ci) {
      f4 Q0 = ci ? q10 : q00, Q1 = ci ? q11 : q01;
      f4 Q2 = ci ? q12 : q02, Q3 = ci ? q13 : q03;
      f4 A0 = ci ? a10 : a00, A1 = ci ? a11 : a01;
      const float* w7 = ci ? w71 : w70;
      float rr_[16] = {Q0.x, Q0.y, Q0.z, Q0.w, Q1.x, Q1.y, Q1.z, Q1.w,
                       Q2.x, Q2.y, Q2.z, Q2.w, Q3.x, Q3.y, Q3.z, Q3.w};
      float x1v[8] = {A0.x, A0.y, A0.z, A0.w, A1.x, A1.y, A1.z, A1.w};
      #pragma unroll
      for (int dxx = 0; dxx < 7; ++dxx) {
        #pragma unroll
        for (int p = 0; p < 8; ++p) {
          acc[dxx][p] = fmaf(w7[dxx], x1v[p] * rr_[p + dxx + 1], acc[dxx][p]);
        }
      }
    }
    __builtin_amdgcn_s_setprio(0);

    bcur = (bcur == 2) ? 0 : bcur + 1;
    bn2 = (bn2 == 2) ? 0 : bn2 + 1;
  }

  if (active) {
    const float sc = 1.0f / 32.0f;
    #pragma unroll
    for (int dxx = 0; dxx < 7; ++dxx) {
      int och = (dy * 7 + dxx) * G_ + g;
      float* op = out + (((size_t)b * 196 + och) * L_ + t) * (size_t)HW_
                      + (size_t)(h0 + h) * W_ + w0;
      f4 o0 = {acc[dxx][0] * sc, acc[dxx][1] * sc,
               acc[dxx][2] * sc, acc[dxx][3] * sc};
      f4 o1 = {acc[dxx][4] * sc, acc[dxx][5] * sc,
               acc[dxx][6] * sc, acc[dxx][7] * sc};
      __builtin_nontemporal_store(o0, (f4*)op);
      __builtin_nontemporal_store(o1, (f4*)(op + 4));
    }
  }
}

extern "C" void kernel_launch(void* const* d_in, const int* in_sizes, int n_in,
                              void* d_out, int out_size, void* d_ws, size_t ws_size,
                              hipStream_t stream) {
  const float* x = (const float*)d_in[0];
  const float* w = (const float*)d_in[1];
  float* o = (float*)d_out;
  // 256 B zeros region for redirected (pad/OOB/dummy) staging lanes
  hipMemsetAsync(d_ws, 0, 256, stream);
  dim3 grid(7168), block(256);
  hipLaunchKernelGGL(wcorr, grid, block, 0, stream, x, w, o, (const float*)d_ws);
}